// Round 2
// baseline (307.041 us; speedup 1.0000x reference)
//
#include <hip/hip_runtime.h>

// Problem constants (static in the reference: SIZES[g] = 256 + 16*g, B=16)
#define IN_DIM   16
#define HID      64
#define OUT      32
#define NGRAPH   16
#define N_TOT    6016
#define N_PAIRS  2349056
#define TOTAL_F4 (N_PAIRS * (OUT / 4))   // 18,792,448 float4 outputs

// sum of squares 1..n
__host__ __device__ constexpr unsigned sumsq(unsigned n) {
    return n * (n + 1u) * (2u * n + 1u) / 6u;
}
// pair offset of graph g: 256*(S(g+15) - S(15)), S(15)=1240
__host__ __device__ constexpr unsigned poff_of(unsigned g) {
    return 256u * (sumsq(g + 15u) - 1240u);
}
static_assert(poff_of(3)  == 222464u,  "poff check");
static_assert(poff_of(15) == 2103040u, "poff check");
static_assert(poff_of(15) + 496u * 496u == (unsigned)N_PAIRS, "total check");

// ---------------------------------------------------------------------------
// Kernel A: per-node MLP  t = relu(ape @ W1 + b1) @ W2 + b2   -> T [N_TOT, 32]
// 8 nodes per block, 32 threads per node.
// ---------------------------------------------------------------------------
__global__ __launch_bounds__(256) void mlp_kernel(
    const float* __restrict__ ape, const float* __restrict__ W1,
    const float* __restrict__ b1,  const float* __restrict__ W2,
    const float* __restrict__ b2,  float* __restrict__ T)
{
    __shared__ float Hs[8][HID];       // 2 KB
    __shared__ float W2s[HID * OUT];   // 8 KB

    // Stage W2 (2048 floats) into LDS
    for (int idx = threadIdx.x; idx < HID * OUT; idx += 256)
        W2s[idx] = W2[idx];

    const int nl   = threadIdx.x >> 5;        // node-local 0..7
    const int c    = threadIdx.x & 31;        // channel 0..31
    const int node = blockIdx.x * 8 + nl;     // grid = 752 -> exactly 6016

    // Stage 1: H[k] for k = c and c+32
    float acc0 = b1[c];
    float acc1 = b1[c + 32];
    const float* a = ape + node * IN_DIM;
#pragma unroll
    for (int d = 0; d < IN_DIM; ++d) {
        const float av = a[d];
        acc0 += av * W1[d * HID + c];
        acc1 += av * W1[d * HID + c + 32];
    }
    Hs[nl][c]      = fmaxf(acc0, 0.0f);
    Hs[nl][c + 32] = fmaxf(acc1, 0.0f);
    __syncthreads();

    // Stage 2: t[c] = b2[c] + sum_k H[k] * W2[k][c]
    float t = b2[c];
#pragma unroll
    for (int k = 0; k < HID; ++k)
        t += Hs[nl][k] * W2s[k * OUT + c];
    T[node * OUT + c] = t;
}

// ---------------------------------------------------------------------------
// Kernel B: out[p*32 + c] = T[start_g + i][c] + T[start_g + j][c]
// Global pair index p -> (g, i, j); one thread per float4 (coalesced stores).
//
// Closed forms (sizes n_g = 16*(16+g)):
//   start[g] = 8*g*(g+31)
//   poff[g]  = 256*(S(g+15) - 1240),  S(n) = n(n+1)(2n+1)/6
// Both the boundary constants and poffg come from the SAME constexpr formula.
// ---------------------------------------------------------------------------
__global__ __launch_bounds__(256) void pair_kernel(
    const float4* __restrict__ T4, float4* __restrict__ out4)
{
    const unsigned q = blockIdx.x * 256u + threadIdx.x;  // float4 index
    if (q >= (unsigned)TOTAL_F4) return;

    const unsigned p  = q >> 3;   // pair index
    const unsigned c4 = q & 7;    // which float4 of the 32-float row

    unsigned g = 0;
#pragma unroll
    for (unsigned k = 1; k < NGRAPH; ++k)
        g += (p >= poff_of(k)) ? 1u : 0u;

    const unsigned poffg = poff_of(g);                 // few VALU ops, exact
    const unsigned n     = 256u + (g << 4);
    const unsigned start = (g * (g + 31u)) << 3;

    const unsigned lp = p - poffg;
    const unsigned i  = (lp >> 4) / (g + 16u);   // floor(lp/16/(16+g)) == lp/n
    const unsigned j  = lp - i * n;

    const float4 va = T4[(start + i) * (OUT / 4) + c4];
    const float4 vb = T4[(start + j) * (OUT / 4) + c4];
    out4[q] = make_float4(va.x + vb.x, va.y + vb.y, va.z + vb.z, va.w + vb.w);
}

extern "C" void kernel_launch(void* const* d_in, const int* in_sizes, int n_in,
                              void* d_out, int out_size, void* d_ws, size_t ws_size,
                              hipStream_t stream) {
    const float* ape = (const float*)d_in[0];
    const float* W1  = (const float*)d_in[1];
    const float* b1  = (const float*)d_in[2];
    const float* W2  = (const float*)d_in[3];
    const float* b2  = (const float*)d_in[4];
    // d_in[5] = batch (unused: sizes are static), d_in[6..8] = scalars

    float* T = (float*)d_ws;   // 6016*32*4 = 770 KB scratch

    mlp_kernel<<<N_TOT / 8, 256, 0, stream>>>(ape, W1, b1, W2, b2, T);
    pair_kernel<<<TOTAL_F4 / 256, 256, 0, stream>>>((const float4*)T,
                                                    (float4*)d_out);
}